// Round 2
// baseline (422.375 us; speedup 1.0000x reference)
//
#include <hip/hip_runtime.h>

typedef unsigned int u32;

// elements per scale = B*g*g*A*85
#define NE0 23566080u   // 16*76*76*3*85
#define NE1 5891520u    // 16*38*38*3*85
#define NE2 1472880u    // 16*19*19*3*85

struct ScaleAcc {
  float sum_coord, sum_conf, sum_bce, sum_neg;
  u32 n_pos, n_neg, max_idx, pad;
};

__device__ __forceinline__ void reduce_and_commit(
    float sc, float sf, float sb, float sn, u32 np, u32 nn, u32 mi, ScaleAcc* acc)
{
  #pragma unroll
  for (int o = 32; o > 0; o >>= 1) {
    sc += __shfl_down(sc, o);
    sf += __shfl_down(sf, o);
    sb += __shfl_down(sb, o);
    sn += __shfl_down(sn, o);
    np += __shfl_down(np, o);
    nn += __shfl_down(nn, o);
    u32 omi = __shfl_down(mi, o);
    mi = omi > mi ? omi : mi;
  }
  __shared__ float shf[4][4];
  __shared__ u32 shu[3][4];
  const int wave = threadIdx.x >> 6;
  const int lane = threadIdx.x & 63;
  if (lane == 0) {
    shf[0][wave] = sc; shf[1][wave] = sf; shf[2][wave] = sb; shf[3][wave] = sn;
    shu[0][wave] = np; shu[1][wave] = nn; shu[2][wave] = mi;
  }
  __syncthreads();
  if (threadIdx.x == 0) {
    float a = 0.f, b = 0.f, c = 0.f, d = 0.f;
    u32 x = 0, y = 0, z = 0;
    #pragma unroll
    for (int w = 0; w < 4; ++w) {
      a += shf[0][w]; b += shf[1][w]; c += shf[2][w]; d += shf[3][w];
      x += shu[0][w]; y += shu[1][w];
      z = shu[2][w] > z ? shu[2][w] : z;
    }
    atomicAdd(&acc->sum_coord, a);
    atomicAdd(&acc->sum_conf, b);
    atomicAdd(&acc->sum_bce, c);
    atomicAdd(&acc->sum_neg, d);
    atomicAdd(&acc->n_pos, x);
    atomicAdd(&acc->n_neg, y);
    atomicMax(&acc->max_idx, z);
  }
  __syncthreads();  // shared arrays reused by the next scale's commit
}

__device__ __forceinline__ void process_scale(
    const float* __restrict__ pred, const float* __restrict__ gt,
    const int* __restrict__ mpos, const int* __restrict__ mneg,
    u32 ngroups, u32 tid, u32 nthreads, ScaleAcc* acc)
{
  float sc = 0.f, sf = 0.f, sb = 0.f, sn = 0.f;
  u32 np = 0, nn = 0, mi = 0;
  const float4* p4 = (const float4*)pred;
  const float4* g4 = (const float4*)gt;
  const int4*   m4 = (const int4*)mneg;
  for (u32 g = tid; g < ngroups; g += nthreads) {
    float4 pv = p4[g];
    float4 gv = g4[g];
    int4   mv = m4[g];
    u32 base = g * 4u;
    u32 cell = base / 85u;           // compiler magic-mul
    u32 ch = base - cell * 85u;
    float ps[4] = {pv.x, pv.y, pv.z, pv.w};
    float gs[4] = {gv.x, gv.y, gv.z, gv.w};
    int   ms[4] = {mv.x, mv.y, mv.z, mv.w};
    #pragma unroll
    for (int j = 0; j < 4; ++j) {
      float x = ps[j], z = gs[j];
      float d = z - x;
      float d2 = d * d;
      if (ms[j]) { sn += d2; nn++; }
      if (mpos[cell]) {
        if (ch == 0u) { np++; mi = cell > mi ? cell : mi; }
        if (ch < 4u)        sc += d2;
        else if (ch == 4u)  sf += d2;
        else                sb += fmaxf(x, 0.f) - x * z + log1pf(__expf(-fabsf(x)));
      }
      ++ch;
      if (ch == 85u) { ch = 0u; ++cell; }
    }
  }
  reduce_and_commit(sc, sf, sb, sn, np, nn, mi, acc);
}

__global__ __launch_bounds__(256) void yolo_main(
    const float* __restrict__ pred0, const float* __restrict__ gt0,
    const int* __restrict__ mp0, const int* __restrict__ mn0,
    const float* __restrict__ pred1, const float* __restrict__ gt1,
    const int* __restrict__ mp1, const int* __restrict__ mn1,
    const float* __restrict__ pred2, const float* __restrict__ gt2,
    const int* __restrict__ mp2, const int* __restrict__ mn2,
    ScaleAcc* ws)
{
  const u32 tid = blockIdx.x * blockDim.x + threadIdx.x;
  const u32 nthreads = gridDim.x * blockDim.x;
  process_scale(pred0, gt0, mp0, mn0, NE0 / 4u, tid, nthreads, &ws[0]);
  process_scale(pred1, gt1, mp1, mn1, NE1 / 4u, tid, nthreads, &ws[1]);
  process_scale(pred2, gt2, mp2, mn2, NE2 / 4u, tid, nthreads, &ws[2]);
}

__global__ void yolo_finalize(const ScaleAcc* __restrict__ ws,
    const float* __restrict__ mod0, const float* __restrict__ mod1,
    const float* __restrict__ mod2, float* __restrict__ out)
{
  const float* mods[3] = {mod0, mod1, mod2};
  float loss = 0.f;
  for (int s = 0; s < 3; ++s) {
    ScaleAcc a = ws[s];
    if (a.n_pos > 0u) {
      float npf = (float)a.n_pos;
      float w = mods[s][a.max_idx * 6u];   // modulus.reshape(-1,6)[idx_last, 0]
      loss += (w * a.sum_coord + a.sum_conf + a.sum_bce * (1.f / 80.f)) / npf;
    }
    if (a.n_neg > 0u) {
      loss += 3.0f * a.sum_neg / (float)a.n_neg;
    }
  }
  out[0] = loss;
}

extern "C" void kernel_launch(void* const* d_in, const int* in_sizes, int n_in,
                              void* d_out, int out_size, void* d_ws, size_t ws_size,
                              hipStream_t stream)
{
  const float* pred0 = (const float*)d_in[0];
  const float* gt0   = (const float*)d_in[1];
  const float* mod0  = (const float*)d_in[2];
  const int*   mp0   = (const int*)d_in[3];
  const int*   mn0   = (const int*)d_in[4];
  const float* pred1 = (const float*)d_in[5];
  const float* gt1   = (const float*)d_in[6];
  const float* mod1  = (const float*)d_in[7];
  const int*   mp1   = (const int*)d_in[8];
  const int*   mn1   = (const int*)d_in[9];
  const float* pred2 = (const float*)d_in[10];
  const float* gt2   = (const float*)d_in[11];
  const float* mod2  = (const float*)d_in[12];
  const int*   mp2   = (const int*)d_in[13];
  const int*   mn2   = (const int*)d_in[14];

  ScaleAcc* ws = (ScaleAcc*)d_ws;
  hipMemsetAsync(d_ws, 0, 3 * sizeof(ScaleAcc), stream);

  yolo_main<<<2048, 256, 0, stream>>>(pred0, gt0, mp0, mn0,
                                      pred1, gt1, mp1, mn1,
                                      pred2, gt2, mp2, mn2, ws);
  yolo_finalize<<<1, 1, 0, stream>>>(ws, mod0, mod1, mod2, (float*)d_out);
}

// Round 3
// 81.011 us; speedup vs baseline: 5.2138x; 5.2138x over previous
//
#include <hip/hip_runtime.h>

typedef unsigned int u32;

// elements per scale = B*g*g*A*85
#define NE0 23566080u   // 16*76*76*3*85
#define NE1 5891520u    // 16*38*38*3*85
#define NE2 1472880u    // 16*19*19*3*85
#define NBLK 2048u

struct ScaleAcc {
  float sum_coord, sum_conf, sum_bce, sum_neg;
  u32 n_pos, n_neg, max_idx, pad;
};

// Block-level reduce, then ONE plain store per block (no atomics: 43k
// same-line device-scope atomic RMWs serialized at the coherence point were
// the 452us critical path — all pipes idle, occupancy 70%).
__device__ __forceinline__ void reduce_and_commit(
    float sc, float sf, float sb, float sn, u32 np, u32 nn, u32 mi,
    ScaleAcc* __restrict__ slot)
{
  #pragma unroll
  for (int o = 32; o > 0; o >>= 1) {
    sc += __shfl_down(sc, o);
    sf += __shfl_down(sf, o);
    sb += __shfl_down(sb, o);
    sn += __shfl_down(sn, o);
    np += __shfl_down(np, o);
    nn += __shfl_down(nn, o);
    u32 omi = __shfl_down(mi, o);
    mi = omi > mi ? omi : mi;
  }
  __shared__ float shf[4][4];
  __shared__ u32 shu[3][4];
  const int wave = threadIdx.x >> 6;
  const int lane = threadIdx.x & 63;
  if (lane == 0) {
    shf[0][wave] = sc; shf[1][wave] = sf; shf[2][wave] = sb; shf[3][wave] = sn;
    shu[0][wave] = np; shu[1][wave] = nn; shu[2][wave] = mi;
  }
  __syncthreads();
  if (threadIdx.x == 0) {
    ScaleAcc a = {0.f, 0.f, 0.f, 0.f, 0u, 0u, 0u, 0u};
    #pragma unroll
    for (int w = 0; w < 4; ++w) {
      a.sum_coord += shf[0][w]; a.sum_conf += shf[1][w];
      a.sum_bce   += shf[2][w]; a.sum_neg  += shf[3][w];
      a.n_pos += shu[0][w]; a.n_neg += shu[1][w];
      a.max_idx = shu[2][w] > a.max_idx ? shu[2][w] : a.max_idx;
    }
    *slot = a;   // plain 32B store to this block's private slot
  }
  __syncthreads();  // shared arrays reused by the next scale's commit
}

__device__ __forceinline__ void process_scale(
    const float* __restrict__ pred, const float* __restrict__ gt,
    const int* __restrict__ mpos, const int* __restrict__ mneg,
    u32 ngroups, u32 tid, u32 nthreads, ScaleAcc* __restrict__ slot)
{
  float sc = 0.f, sf = 0.f, sb = 0.f, sn = 0.f;
  u32 np = 0, nn = 0, mi = 0;
  const float4* p4 = (const float4*)pred;
  const float4* g4 = (const float4*)gt;
  const int4*   m4 = (const int4*)mneg;
  for (u32 g = tid; g < ngroups; g += nthreads) {
    float4 pv = p4[g];
    float4 gv = g4[g];
    int4   mv = m4[g];
    u32 base = g * 4u;
    u32 cell = base / 85u;           // compiler magic-mul
    u32 ch = base - cell * 85u;
    float ps[4] = {pv.x, pv.y, pv.z, pv.w};
    float gs[4] = {gv.x, gv.y, gv.z, gv.w};
    int   ms[4] = {mv.x, mv.y, mv.z, mv.w};
    #pragma unroll
    for (int j = 0; j < 4; ++j) {
      float x = ps[j], z = gs[j];
      float d = z - x;
      float d2 = d * d;
      if (ms[j]) { sn += d2; nn++; }
      if (mpos[cell]) {
        if (ch == 0u) { np++; mi = cell > mi ? cell : mi; }
        if (ch < 4u)        sc += d2;
        else if (ch == 4u)  sf += d2;
        else                sb += fmaxf(x, 0.f) - x * z + log1pf(__expf(-fabsf(x)));
      }
      ++ch;
      if (ch == 85u) { ch = 0u; ++cell; }
    }
  }
  reduce_and_commit(sc, sf, sb, sn, np, nn, mi, slot);
}

__global__ __launch_bounds__(256) void yolo_main(
    const float* __restrict__ pred0, const float* __restrict__ gt0,
    const int* __restrict__ mp0, const int* __restrict__ mn0,
    const float* __restrict__ pred1, const float* __restrict__ gt1,
    const int* __restrict__ mp1, const int* __restrict__ mn1,
    const float* __restrict__ pred2, const float* __restrict__ gt2,
    const int* __restrict__ mp2, const int* __restrict__ mn2,
    ScaleAcc* __restrict__ ws)
{
  const u32 tid = blockIdx.x * blockDim.x + threadIdx.x;
  const u32 nthreads = gridDim.x * blockDim.x;
  process_scale(pred0, gt0, mp0, mn0, NE0 / 4u, tid, nthreads, &ws[0 * NBLK + blockIdx.x]);
  process_scale(pred1, gt1, mp1, mn1, NE1 / 4u, tid, nthreads, &ws[1 * NBLK + blockIdx.x]);
  process_scale(pred2, gt2, mp2, mn2, NE2 / 4u, tid, nthreads, &ws[2 * NBLK + blockIdx.x]);
}

// Single-block second stage: reduce 2048 partials/scale + finalize the loss.
__global__ __launch_bounds__(256) void yolo_reduce(
    const ScaleAcc* __restrict__ ws,
    const float* __restrict__ mod0, const float* __restrict__ mod1,
    const float* __restrict__ mod2, float* __restrict__ out)
{
  const float* mods[3] = {mod0, mod1, mod2};
  __shared__ float shf[4][4];
  __shared__ u32 shu[3][4];
  const int wave = threadIdx.x >> 6;
  const int lane = threadIdx.x & 63;
  float loss = 0.f;   // only thread 0's copy matters
  for (int s = 0; s < 3; ++s) {
    float sc = 0.f, sf = 0.f, sb = 0.f, sn = 0.f;
    u32 np = 0, nn = 0, mi = 0;
    for (u32 t = threadIdx.x; t < NBLK; t += 256u) {
      ScaleAcc a = ws[(u32)s * NBLK + t];
      sc += a.sum_coord; sf += a.sum_conf; sb += a.sum_bce; sn += a.sum_neg;
      np += a.n_pos; nn += a.n_neg;
      mi = a.max_idx > mi ? a.max_idx : mi;
    }
    #pragma unroll
    for (int o = 32; o > 0; o >>= 1) {
      sc += __shfl_down(sc, o);
      sf += __shfl_down(sf, o);
      sb += __shfl_down(sb, o);
      sn += __shfl_down(sn, o);
      np += __shfl_down(np, o);
      nn += __shfl_down(nn, o);
      u32 omi = __shfl_down(mi, o);
      mi = omi > mi ? omi : mi;
    }
    if (lane == 0) {
      shf[0][wave] = sc; shf[1][wave] = sf; shf[2][wave] = sb; shf[3][wave] = sn;
      shu[0][wave] = np; shu[1][wave] = nn; shu[2][wave] = mi;
    }
    __syncthreads();
    if (threadIdx.x == 0) {
      float a = 0.f, b = 0.f, c = 0.f, d = 0.f;
      u32 x = 0, y = 0, z = 0;
      #pragma unroll
      for (int w = 0; w < 4; ++w) {
        a += shf[0][w]; b += shf[1][w]; c += shf[2][w]; d += shf[3][w];
        x += shu[0][w]; y += shu[1][w];
        z = shu[2][w] > z ? shu[2][w] : z;
      }
      if (x > 0u) {
        float npf = (float)x;
        float w_last = mods[s][z * 6u];  // modulus.reshape(-1,6)[idx_last, 0]
        loss += (w_last * a + b + c * (1.f / 80.f)) / npf;
      }
      if (y > 0u) {
        loss += 3.0f * d / (float)y;
      }
    }
    __syncthreads();
  }
  if (threadIdx.x == 0) out[0] = loss;
}

extern "C" void kernel_launch(void* const* d_in, const int* in_sizes, int n_in,
                              void* d_out, int out_size, void* d_ws, size_t ws_size,
                              hipStream_t stream)
{
  const float* pred0 = (const float*)d_in[0];
  const float* gt0   = (const float*)d_in[1];
  const float* mod0  = (const float*)d_in[2];
  const int*   mp0   = (const int*)d_in[3];
  const int*   mn0   = (const int*)d_in[4];
  const float* pred1 = (const float*)d_in[5];
  const float* gt1   = (const float*)d_in[6];
  const float* mod1  = (const float*)d_in[7];
  const int*   mp1   = (const int*)d_in[8];
  const int*   mn1   = (const int*)d_in[9];
  const float* pred2 = (const float*)d_in[10];
  const float* gt2   = (const float*)d_in[11];
  const float* mod2  = (const float*)d_in[12];
  const int*   mp2   = (const int*)d_in[13];
  const int*   mn2   = (const int*)d_in[14];

  ScaleAcc* ws = (ScaleAcc*)d_ws;   // 3*2048*32B = 196 KB, every slot written

  yolo_main<<<NBLK, 256, 0, stream>>>(pred0, gt0, mp0, mn0,
                                      pred1, gt1, mp1, mn1,
                                      pred2, gt2, mp2, mn2, ws);
  yolo_reduce<<<1, 256, 0, stream>>>(ws, mod0, mod1, mod2, (float*)d_out);
}